// Round 2
// baseline (111.424 us; speedup 1.0000x reference)
//
#include <hip/hip_runtime.h>
#include <math.h>

#define FLT_BIG 3.0e38f
#define HIST_BINS 16384   // float bits >> 18 : sign(0)+exp(8)+mant(5)

typedef short short8 __attribute__((ext_vector_type(8)));
typedef float floatx16 __attribute__((ext_vector_type(16)));

union U4S8 { uint4 u; short8 s; };

// round-to-nearest-even f32 -> bf16 bits
static __device__ __forceinline__ unsigned int f2bf(float f) {
    unsigned int u = __float_as_uint(f);
    return (u + 0x7FFFu + ((u >> 16) & 1u)) >> 16;
}
static __device__ __forceinline__ float bf2f(unsigned int b) {
    return __uint_as_float(b << 16);
}

// Tiny counter-zero kernel (replaces hipMemsetAsync: plain launch node is
// guaranteed graph-capturable and replays with the graph).
__global__ void zero_cnt_kernel(unsigned int* __restrict__ cnt, int B)
{
    if ((int)threadIdx.x < B) cnt[threadIdx.x] = 0u;
}

// Fused kernel: chamfer (MFMA 32x32x16) + last-block-per-batch histogram select.
// Chamfer part identical to the verified 2-kernel version:
//   D[i][j] = -p_i.q_j + 0.5|q_j|^2 + 0.5|p_i|^2 = 0.5 d^2
// Block 256 = 4 waves: wave w -> rays (w&1)*32..+32, M-half (w>>1).
// Grid (N/64, B). Dynamic LDS: max(M*16B, HIST_BINS*4B) = 64KB -> 2 blocks/CU.
// After writing its 64 d0 values, each block bumps cnt[b] (device-scope).
// The LAST block of batch b reuses its dynamic LDS as the histogram and runs
// the selection for that batch -- selection overlaps the other batches'
// chamfer instead of serializing behind the whole grid.
__global__ __launch_bounds__(256, 2) void chamfer_fused_kernel(
    const float* __restrict__ cparam,   // B x 25
    const float* __restrict__ depth,    // B x N
    const float* __restrict__ pc,       // B x M x 3
    float* __restrict__ d0,             // B x N scratch (clamped >= 0)
    unsigned int* __restrict__ cnt,     // B counters (pre-zeroed)
    float* __restrict__ out,            // B x 1
    int N, int M, int R, int K)
{
    const int b    = blockIdx.y;
    const int tid  = threadIdx.x;
    const int lane = tid & 63;
    const int wv   = tid >> 6;           // wave 0..3
    const int row  = lane & 31;          // A-row / B-col / D-col
    const int half = lane >> 5;          // k-group: 0 -> k0..7, 1 -> k8..15

    extern __shared__ uint4 sld[];       // M entries of 16B (8 bf16 B-frag); reused as hist
    __shared__ float smin[4][32];
    __shared__ int   s_last;
    // selection-phase statics
    __shared__ unsigned int spart[256];
    __shared__ unsigned int s_selbin, s_krem;
    __shared__ unsigned int subcnt[32];
    __shared__ float        subsum[32];
    __shared__ float        s_below;

    // ---- stage point cloud as pre-packed B-fragments ----
    const float* pcb = pc + (size_t)b * M * 3;
    const int Ms = M >> 8;               // points per thread (16)
    for (int s = 0; s < Ms; s++) {
        const int idx = s * 256 + tid;
        const float x = pcb[idx * 3 + 0];
        const float y = pcb[idx * 3 + 1];
        const float z = pcb[idx * 3 + 2];
        const float hq = 0.5f * (x * x + y * y + z * z);
        uint4 u;
        u.x = f2bf(x) | (f2bf(y) << 16);
        u.y = f2bf(z) | (f2bf(hq) << 16);
        u.z = 0x3F803F80u;               // [1.0, 1.0] multiplies hp_hi, hp_lo
        u.w = 0u;
        sld[idx] = u;
    }
    __syncthreads();

    // ---- camera + per-lane ray ----
    const float* cb = cparam + (size_t)b * 25;
    const float fx = cb[16], sk = cb[17], cx = cb[18];
    const float fy = cb[20], cy = cb[21];

    const int nbase = blockIdx.x * 64;
    const int n  = nbase + (wv & 1) * 32 + row;
    const int i0 = n / R;
    const int j0 = n - i0 * R;
    const float x_cam = (j0 + 0.5f) / (float)R;
    const float y_cam = (i0 + 0.5f) / (float)R;
    const float x_lift = (x_cam - cx + cy * sk / fy - sk * y_cam / fy) / fx;
    const float y_lift = (y_cam - cy) / fy;
    const float dxw = cb[0] * x_lift + cb[1] * y_lift + cb[2];
    const float dyw = cb[4] * x_lift + cb[5] * y_lift + cb[6];
    const float dzw = cb[8] * x_lift + cb[9] * y_lift + cb[10];
    const float inv = 1.0f / sqrtf(dxw * dxw + dyw * dyw + dzw * dzw);
    const float dep = depth[(size_t)b * N + n];
    const float px = cb[3]  + dep * dxw * inv;
    const float py = cb[7]  + dep * dyw * inv;
    const float pz = cb[11] + dep * dzw * inv;

    const float hp = 0.5f * (px * px + py * py + pz * pz);
    const unsigned int hp_hi = f2bf(hp);
    const unsigned int hp_lo = f2bf(hp - bf2f(hp_hi));

    U4S8 af;
    af.u = make_uint4(0u, 0u, 0u, 0u);
    if (half == 0) {                     // k=8..15 (upper lanes) stay zero
        af.u.x = f2bf(-px) | (f2bf(-py) << 16);
        af.u.y = f2bf(-pz) | (0x3F80u << 16);      // [-pz, 1.0]
        af.u.z = hp_hi | (hp_lo << 16);
    }
    const short8 afrag = af.s;
    const floatx16 zero16 = {0,0,0,0,0,0,0,0,0,0,0,0,0,0,0,0};

    float minsA[16], minsB[16];
    #pragma unroll
    for (int t = 0; t < 16; t++) { minsA[t] = FLT_BIG; minsB[t] = FLT_BIG; }

    // ---- main loop: this wave's M-half, 64 B-frags of 32 points ----
    const int fbase = (wv >> 1) * 64;    // frag index base (frag = 32 points)
    for (int f = 0; f < 64; f += 8) {
        uint4 bu[8];
        #pragma unroll
        for (int mm = 0; mm < 8; mm++)
            bu[mm] = sld[((fbase + f + mm) << 5) + row];
        #pragma unroll
        for (int mm = 0; mm < 8; mm++) {
            U4S8 bf; bf.u = bu[mm];
            floatx16 d = __builtin_amdgcn_mfma_f32_32x32x16_bf16(
                             afrag, bf.s, zero16, 0, 0, 0);
            if (mm & 1) {
                #pragma unroll
                for (int t = 0; t < 16; t++) minsB[t] = fminf(minsB[t], d[t]);
            } else {
                #pragma unroll
                for (int t = 0; t < 16; t++) minsA[t] = fminf(minsA[t], d[t]);
            }
        }
    }

    // ---- reduce over the 32 cols (within each 32-lane half) ----
    #pragma unroll
    for (int t = 0; t < 16; t++) {
        float v = fminf(minsA[t], minsB[t]);
        v = fminf(v, __shfl_xor(v, 1));
        v = fminf(v, __shfl_xor(v, 2));
        v = fminf(v, __shfl_xor(v, 4));
        v = fminf(v, __shfl_xor(v, 8));
        v = fminf(v, __shfl_xor(v, 16));
        minsA[t] = v;
    }
    // rows for reg t: (t&3) + 8*(t>>2) + 4*half
    if (row == 0) {
        #pragma unroll
        for (int t = 0; t < 16; t++)
            smin[wv][(t & 3) + 8 * (t >> 2) + 4 * half] = minsA[t];
    }
    __syncthreads();

    // combine M-halves: rays 0-31 in waves {0,2}, rays 32-63 in waves {1,3}
    if (tid < 64) {
        const int g  = tid >> 5;         // 0 or 1
        const int rr = tid & 31;
        const float v = fminf(smin[g][rr], smin[g + 2][rr]);
        d0[(size_t)b * N + nbase + tid] = fmaxf(2.0f * v, 0.0f);
    }

    // ---- last-block handoff (release: fence by writers, then t0's atomic) ----
    __threadfence();
    __syncthreads();
    if (tid == 0) {
        const unsigned int done = atomicAdd(&cnt[b], 1u);
        s_last = (done == gridDim.x - 1) ? 1 : 0;
    }
    __syncthreads();
    if (!s_last) return;

    // ================= selection phase (last block of batch b only) =========
    __threadfence();                      // acquire: see all blocks' d0 writes
    unsigned int* hist = (unsigned int*)sld;   // reuse 64KB dynamic LDS

    for (int t2 = tid; t2 < HIST_BINS; t2 += 256) hist[t2] = 0u;
    if (tid < 32) { subcnt[tid] = 0u; subsum[tid] = 0.0f; }
    if (tid == 0) s_below = 0.0f;
    __syncthreads();

    unsigned int key[16];
    #pragma unroll
    for (int t2 = 0; t2 < 16; t2++)
        key[t2] = __float_as_uint(d0[(size_t)b * N + t2 * 256 + tid]);
    #pragma unroll
    for (int t2 = 0; t2 < 16; t2++)
        atomicAdd(&hist[key[t2] >> 18], 1u);
    __syncthreads();

    unsigned int psum = 0u;
    #pragma unroll 8
    for (int i2 = 0; i2 < 64; i2++)
        psum += hist[(tid << 6) + ((i2 + tid) & 63)];
    spart[tid] = psum;
    __syncthreads();

    unsigned int cbef = 0u;
    for (int i2 = 0; i2 < tid; i2++) cbef += spart[i2];
    if (cbef < (unsigned int)K && (unsigned int)K <= cbef + psum) {
        unsigned int k2 = (unsigned int)K - cbef;
        unsigned int sel = 0u;
        for (int i2 = 0; i2 < 64; i2++) {
            unsigned int h = hist[(tid << 6) + i2];
            if (k2 <= h) { sel = (tid << 6) + i2; break; }
            k2 -= h;
        }
        s_selbin = sel;
        s_krem   = k2;
    }
    __syncthreads();

    const unsigned int selbin = s_selbin;
    float sumb = 0.0f;
    #pragma unroll
    for (int t2 = 0; t2 < 16; t2++) {
        const unsigned int bin = key[t2] >> 18;
        const float v = __uint_as_float(key[t2]);
        if (bin < selbin) sumb += v;
        if (bin == selbin) {
            const unsigned int sub = (key[t2] >> 13) & 31u;
            atomicAdd(&subcnt[sub], 1u);
            atomicAdd(&subsum[sub], v);
        }
    }
    atomicAdd(&s_below, sumb);
    __syncthreads();

    if (tid == 0) {
        unsigned int k2 = s_krem;
        float s = s_below;
        for (int i2 = 0; i2 < 32; i2++) {
            unsigned int h = subcnt[i2];
            if (k2 <= h) {
                s += (h ? (subsum[i2] * ((float)k2 / (float)h)) : 0.0f);
                break;
            }
            s += subsum[i2];
            k2 -= h;
        }
        out[b] = 2.0f * s / (float)K;
    }
}

extern "C" void kernel_launch(void* const* d_in, const int* in_sizes, int n_in,
                              void* d_out, int out_size, void* d_ws, size_t ws_size,
                              hipStream_t stream)
{
    const float* c   = (const float*)d_in[0];
    const float* dep = (const float*)d_in[1];
    const float* pc  = (const float*)d_in[2];
    float* out = (float*)d_out;

    const int B = in_sizes[0] / 25;
    const int N = in_sizes[1] / B;     // 4096 (= 16*256, assumed by selection)
    const int M = in_sizes[2] / (3 * B);
    int R = 1; while (R * R < N) R++;
    const int K = ((N < M) ? N : M) / 2;

    float* d0 = (float*)d_ws;          // B*N floats of scratch
    unsigned int* cnt = (unsigned int*)((char*)d_ws + (size_t)B * N * sizeof(float));

    // per-replay zero of the B completion counters (poison-proof, capture-safe)
    hipLaunchKernelGGL(zero_cnt_kernel, dim3(1), dim3(64), 0, stream, cnt, B);

    size_t ldsA = (size_t)M * sizeof(uint4);                // 64KB point frags
    size_t ldsH = (size_t)HIST_BINS * sizeof(unsigned int); // 64KB hist
    size_t lds  = ldsA > ldsH ? ldsA : ldsH;

    dim3 grid(N / 64, B);
    hipLaunchKernelGGL(chamfer_fused_kernel, grid, dim3(256), lds, stream,
                       c, dep, pc, d0, cnt, out, N, M, R, K);
}

// Round 3
// 82.622 us; speedup vs baseline: 1.3486x; 1.3486x over previous
//
#include <hip/hip_runtime.h>
#include <math.h>

#define FLT_BIG 3.0e38f
#define HIST_BINS 16384   // float bits >> 18 : sign(0)+exp(8)+mant(5)

typedef short short8 __attribute__((ext_vector_type(8)));
typedef float floatx16 __attribute__((ext_vector_type(16)));

union U4S8 { uint4 u; short8 s; };

// round-to-nearest-even f32 -> bf16 bits
static __device__ __forceinline__ unsigned int f2bf(float f) {
    unsigned int u = __float_as_uint(f);
    return (u + 0x7FFFu + ((u >> 16) & 1u)) >> 16;
}
static __device__ __forceinline__ float bf2f(unsigned int b) {
    return __uint_as_float(b << 16);
}

// Kernel P: pack point cloud into MFMA B-fragments ONCE (shared by all 64
// blocks per batch via L2/LLC, instead of each block re-staging + re-packing
// the same 48KB into its own LDS).
// frag[i] (16B): [x,y | z,hq | 1,1 | 0,0] as bf16 pairs, hq = 0.5|q|^2.
__global__ __launch_bounds__(256) void pack_frags_kernel(
    const float* __restrict__ pc,       // (B*M) x 3
    uint4* __restrict__ frags,          // (B*M) entries
    int total)
{
    const int idx = blockIdx.x * 256 + threadIdx.x;
    if (idx >= total) return;
    const float x = pc[idx * 3 + 0];
    const float y = pc[idx * 3 + 1];
    const float z = pc[idx * 3 + 2];
    const float hq = 0.5f * (x * x + y * y + z * z);
    uint4 u;
    u.x = f2bf(x) | (f2bf(y) << 16);
    u.y = f2bf(z) | (f2bf(hq) << 16);
    u.z = 0x3F803F80u;                  // [1.0, 1.0] multiplies hp_hi, hp_lo
    u.w = 0u;
    frags[idx] = u;
}

// Kernel A': chamfer via MFMA 32x32x16, fragments read straight from L2.
//   D[i][j] = -p_i.q_j + 0.5|q_j|^2 + 0.5|p_i|^2 = 0.5 d^2
// K-slots (k=0..7): A=[-p.x,-p.y,-p.z, 1, hp_hi, hp_lo, 0, 0]
//                   B=[ q.x, q.y, q.z, hq,  1,    1,   0, 0]
// A upper k-lanes (half==1) are zero -> both 32-lane halves read the same
// 16B point frag (broadcast).
// Block 256 = 4 waves, ALL on the same 32 rays; wave wv covers M-quarter wv.
// Grid (N/32, B) = 1024 blocks -> 4 blocks/CU, 16 waves/CU (no big LDS!).
__global__ __launch_bounds__(256, 4) void chamfer_mfma_kernel(
    const float* __restrict__ cparam,   // B x 25
    const float* __restrict__ depth,    // B x N
    const uint4* __restrict__ frags,    // B x M packed frags
    float* __restrict__ d0,             // B x N (clamped >= 0)
    int N, int M, int R)
{
    const int b    = blockIdx.y;
    const int tid  = threadIdx.x;
    const int lane = tid & 63;
    const int wv   = tid >> 6;           // wave 0..3 -> M-quarter
    const int row  = lane & 31;          // A-row / B-col / D-col
    const int half = lane >> 5;          // k-group: 0 -> k0..7, 1 -> k8..15

    __shared__ float smin[4][32];

    // ---- camera + per-lane ray (same 32 rays for all 4 waves) ----
    const float* cb = cparam + (size_t)b * 25;
    const float fx = cb[16], sk = cb[17], cx = cb[18];
    const float fy = cb[20], cy = cb[21];

    const int nbase = blockIdx.x * 32;
    const int n  = nbase + row;
    const int i0 = n / R;
    const int j0 = n - i0 * R;
    const float x_cam = (j0 + 0.5f) / (float)R;
    const float y_cam = (i0 + 0.5f) / (float)R;
    const float x_lift = (x_cam - cx + cy * sk / fy - sk * y_cam / fy) / fx;
    const float y_lift = (y_cam - cy) / fy;
    const float dxw = cb[0] * x_lift + cb[1] * y_lift + cb[2];
    const float dyw = cb[4] * x_lift + cb[5] * y_lift + cb[6];
    const float dzw = cb[8] * x_lift + cb[9] * y_lift + cb[10];
    const float inv = 1.0f / sqrtf(dxw * dxw + dyw * dyw + dzw * dzw);
    const float dep = depth[(size_t)b * N + n];
    const float px = cb[3]  + dep * dxw * inv;
    const float py = cb[7]  + dep * dyw * inv;
    const float pz = cb[11] + dep * dzw * inv;

    const float hp = 0.5f * (px * px + py * py + pz * pz);
    const unsigned int hp_hi = f2bf(hp);
    const unsigned int hp_lo = f2bf(hp - bf2f(hp_hi));

    U4S8 af;
    af.u = make_uint4(0u, 0u, 0u, 0u);
    if (half == 0) {                     // k=8..15 (upper lanes) stay zero
        af.u.x = f2bf(-px) | (f2bf(-py) << 16);
        af.u.y = f2bf(-pz) | (0x3F80u << 16);      // [-pz, 1.0]
        af.u.z = hp_hi | (hp_lo << 16);
    }
    const short8 afrag = af.s;
    const floatx16 zero16 = {0,0,0,0,0,0,0,0,0,0,0,0,0,0,0,0};

    float minsA[16], minsB[16];
    #pragma unroll
    for (int t = 0; t < 16; t++) { minsA[t] = FLT_BIG; minsB[t] = FLT_BIG; }

    // ---- main loop: this wave's M-quarter, 32 frags of 32 points, from L2 ----
    const uint4* fb = frags + (size_t)b * M + (wv << 10);   // wv * 1024 points
    for (int f = 0; f < 32; f += 8) {
        uint4 bu[8];
        #pragma unroll
        for (int mm = 0; mm < 8; mm++)
            bu[mm] = fb[((f + mm) << 5) + row];
        #pragma unroll
        for (int mm = 0; mm < 8; mm++) {
            U4S8 bf; bf.u = bu[mm];
            floatx16 d = __builtin_amdgcn_mfma_f32_32x32x16_bf16(
                             afrag, bf.s, zero16, 0, 0, 0);
            if (mm & 1) {
                #pragma unroll
                for (int t = 0; t < 16; t++) minsB[t] = fminf(minsB[t], d[t]);
            } else {
                #pragma unroll
                for (int t = 0; t < 16; t++) minsA[t] = fminf(minsA[t], d[t]);
            }
        }
    }

    // ---- reduce over the 32 cols (within each 32-lane half) ----
    #pragma unroll
    for (int t = 0; t < 16; t++) {
        float v = fminf(minsA[t], minsB[t]);
        v = fminf(v, __shfl_xor(v, 1));
        v = fminf(v, __shfl_xor(v, 2));
        v = fminf(v, __shfl_xor(v, 4));
        v = fminf(v, __shfl_xor(v, 8));
        v = fminf(v, __shfl_xor(v, 16));
        minsA[t] = v;
    }
    // rows for reg t: (t&3) + 8*(t>>2) + 4*half
    if (row == 0) {
        #pragma unroll
        for (int t = 0; t < 16; t++)
            smin[wv][(t & 3) + 8 * (t >> 2) + 4 * half] = minsA[t];
    }
    __syncthreads();

    // combine the 4 M-quarters
    if (tid < 32) {
        const float v = fminf(fminf(smin[0][tid], smin[1][tid]),
                              fminf(smin[2][tid], smin[3][tid]));
        d0[(size_t)b * N + nbase + tid] = fmaxf(2.0f * v, 0.0f);
    }
}

// Kernel B: per-batch histogram select (byte-identical to the verified version).
__global__ __launch_bounds__(256, 1) void select_mean_kernel(
    const float* __restrict__ d0,
    float* __restrict__ out,
    int N, int K)
{
    const int b   = blockIdx.x;
    const int tid = threadIdx.x;

    extern __shared__ unsigned int hist[];   // HIST_BINS
    __shared__ unsigned int spart[256];
    __shared__ unsigned int s_selbin, s_krem;
    __shared__ unsigned int subcnt[32];
    __shared__ float        subsum[32];
    __shared__ float        s_below;

    for (int t2 = tid; t2 < HIST_BINS; t2 += 256) hist[t2] = 0u;
    if (tid < 32) { subcnt[tid] = 0u; subsum[tid] = 0.0f; }
    if (tid == 0) s_below = 0.0f;
    __syncthreads();

    unsigned int key[16];
    #pragma unroll
    for (int t2 = 0; t2 < 16; t2++)
        key[t2] = __float_as_uint(d0[(size_t)b * N + t2 * 256 + tid]);
    #pragma unroll
    for (int t2 = 0; t2 < 16; t2++)
        atomicAdd(&hist[key[t2] >> 18], 1u);
    __syncthreads();

    unsigned int psum = 0u;
    #pragma unroll 8
    for (int i2 = 0; i2 < 64; i2++)
        psum += hist[(tid << 6) + ((i2 + tid) & 63)];
    spart[tid] = psum;
    __syncthreads();

    unsigned int cbef = 0u;
    for (int i2 = 0; i2 < tid; i2++) cbef += spart[i2];
    if (cbef < (unsigned int)K && (unsigned int)K <= cbef + psum) {
        unsigned int k2 = (unsigned int)K - cbef;
        unsigned int sel = 0u;
        for (int i2 = 0; i2 < 64; i2++) {
            unsigned int h = hist[(tid << 6) + i2];
            if (k2 <= h) { sel = (tid << 6) + i2; break; }
            k2 -= h;
        }
        s_selbin = sel;
        s_krem   = k2;
    }
    __syncthreads();

    const unsigned int selbin = s_selbin;
    float sumb = 0.0f;
    #pragma unroll
    for (int t2 = 0; t2 < 16; t2++) {
        const unsigned int bin = key[t2] >> 18;
        const float v = __uint_as_float(key[t2]);
        if (bin < selbin) sumb += v;
        if (bin == selbin) {
            const unsigned int sub = (key[t2] >> 13) & 31u;
            atomicAdd(&subcnt[sub], 1u);
            atomicAdd(&subsum[sub], v);
        }
    }
    atomicAdd(&s_below, sumb);
    __syncthreads();

    if (tid == 0) {
        unsigned int k2 = s_krem;
        float s = s_below;
        for (int i2 = 0; i2 < 32; i2++) {
            unsigned int h = subcnt[i2];
            if (k2 <= h) {
                s += (h ? (subsum[i2] * ((float)k2 / (float)h)) : 0.0f);
                break;
            }
            s += subsum[i2];
            k2 -= h;
        }
        out[b] = 2.0f * s / (float)K;
    }
}

extern "C" void kernel_launch(void* const* d_in, const int* in_sizes, int n_in,
                              void* d_out, int out_size, void* d_ws, size_t ws_size,
                              hipStream_t stream)
{
    const float* c   = (const float*)d_in[0];
    const float* dep = (const float*)d_in[1];
    const float* pc  = (const float*)d_in[2];
    float* out = (float*)d_out;

    const int B = in_sizes[0] / 25;
    const int N = in_sizes[1] / B;     // 4096 (= 16*256, assumed by kernel B)
    const int M = in_sizes[2] / (3 * B);
    int R = 1; while (R * R < N) R++;
    const int K = ((N < M) ? N : M) / 2;

    float* d0    = (float*)d_ws;                                   // B*N floats
    uint4* frags = (uint4*)((char*)d_ws + (size_t)B * N * sizeof(float)); // B*M*16B

    const int total = B * M;
    hipLaunchKernelGGL(pack_frags_kernel, dim3((total + 255) / 256), dim3(256),
                       0, stream, pc, frags, total);

    dim3 gridA(N / 32, B);
    hipLaunchKernelGGL(chamfer_mfma_kernel, gridA, dim3(256), 0, stream,
                       c, dep, frags, d0, N, M, R);

    size_t ldsB = (size_t)HIST_BINS * sizeof(unsigned int);
    hipLaunchKernelGGL(select_mean_kernel, dim3(B), dim3(256), ldsB, stream,
                       d0, out, N, K);
}

// Round 4
// 81.665 us; speedup vs baseline: 1.3644x; 1.0117x over previous
//
#include <hip/hip_runtime.h>
#include <math.h>

#define FLT_BIG 3.0e38f
#define HIST_BINS 16384   // float bits >> 18 : sign(0)+exp(8)+mant(5)

typedef short short8 __attribute__((ext_vector_type(8)));
typedef float floatx16 __attribute__((ext_vector_type(16)));

union U4S8 { uint4 u; short8 s; };

// round-to-nearest-even f32 -> bf16 bits
static __device__ __forceinline__ unsigned int f2bf(float f) {
    unsigned int u = __float_as_uint(f);
    return (u + 0x7FFFu + ((u >> 16) & 1u)) >> 16;
}
static __device__ __forceinline__ float bf2f(unsigned int b) {
    return __uint_as_float(b << 16);
}

// Kernel A'': chamfer via MFMA 32x32x16.
//   D[i][j] = -p_i.q_j + 0.5|q_j|^2 + 0.5|p_i|^2 = 0.5 d^2
// K-slots (k=0..7): A=[-p.x,-p.y,-p.z, 1, hp_hi, hp_lo, 0, 0]
//                   B=[ q.x, q.y, q.z, hq,  1,    1,   0, 0]
// B-frag upper half is CONSTANT [1,1,0,0] -> LDS stores only 8B/point
// (x,y | z,hq) = 32KB for M=4096; uint4 rebuilt in-register.
// Block = 1024 threads = 16 waves, 128 rays/block.
// Wave w: ray-group (w&3) (32 rays), M-quarter (w>>2) (1024 pts = 32 frags).
// Grid (N/128, B) = 256 blocks = exactly 1/CU: one pass, no tail, and the
// 48KB point-cloud repack happens once per 128 rays (4x less than round 0)
// with NO extra dependent dispatch (round 3's pack-kernel gap ate its win).
__global__ __launch_bounds__(1024) void chamfer_mfma_kernel(
    const float* __restrict__ cparam,   // B x 25
    const float* __restrict__ depth,    // B x N
    const float* __restrict__ pc,       // B x M x 3
    float* __restrict__ d0,             // B x N (clamped >= 0)
    int N, int M, int R)
{
    const int b    = blockIdx.y;
    const int tid  = threadIdx.x;
    const int lane = tid & 63;
    const int wv   = tid >> 6;           // wave 0..15
    const int rg   = wv & 3;             // ray group (32 rays each)
    const int mq   = wv >> 2;            // M quarter
    const int row  = lane & 31;          // A-row / B-col / D-col
    const int half = lane >> 5;          // k-group: 0 -> k0..7, 1 -> k8..15

    extern __shared__ uint2 sld[];       // M entries of 8B (x,y | z,hq)
    __shared__ float smin[16][32];

    // ---- stage point cloud once per block (8B/point) ----
    const float* pcb = pc + (size_t)b * M * 3;
    const int Ms = M >> 10;              // points per thread (4)
    for (int s = 0; s < Ms; s++) {
        const int idx = (s << 10) + tid;
        const float x = pcb[idx * 3 + 0];
        const float y = pcb[idx * 3 + 1];
        const float z = pcb[idx * 3 + 2];
        const float hq = 0.5f * (x * x + y * y + z * z);
        uint2 u;
        u.x = f2bf(x) | (f2bf(y) << 16);
        u.y = f2bf(z) | (f2bf(hq) << 16);
        sld[idx] = u;
    }

    // ---- camera + per-lane ray (overlaps staging loads) ----
    const float* cb = cparam + (size_t)b * 25;
    const float fx = cb[16], sk = cb[17], cx = cb[18];
    const float fy = cb[20], cy = cb[21];

    const int nbase = blockIdx.x * 128;
    const int n  = nbase + rg * 32 + row;
    const int i0 = n / R;
    const int j0 = n - i0 * R;
    const float x_cam = (j0 + 0.5f) / (float)R;
    const float y_cam = (i0 + 0.5f) / (float)R;
    const float x_lift = (x_cam - cx + cy * sk / fy - sk * y_cam / fy) / fx;
    const float y_lift = (y_cam - cy) / fy;
    const float dxw = cb[0] * x_lift + cb[1] * y_lift + cb[2];
    const float dyw = cb[4] * x_lift + cb[5] * y_lift + cb[6];
    const float dzw = cb[8] * x_lift + cb[9] * y_lift + cb[10];
    const float inv = 1.0f / sqrtf(dxw * dxw + dyw * dyw + dzw * dzw);
    const float dep = depth[(size_t)b * N + n];
    const float px = cb[3]  + dep * dxw * inv;
    const float py = cb[7]  + dep * dyw * inv;
    const float pz = cb[11] + dep * dzw * inv;

    const float hp = 0.5f * (px * px + py * py + pz * pz);
    const unsigned int hp_hi = f2bf(hp);
    const unsigned int hp_lo = f2bf(hp - bf2f(hp_hi));

    U4S8 af;
    af.u = make_uint4(0u, 0u, 0u, 0u);
    if (half == 0) {                     // k=8..15 (upper lanes) stay zero
        af.u.x = f2bf(-px) | (f2bf(-py) << 16);
        af.u.y = f2bf(-pz) | (0x3F80u << 16);      // [-pz, 1.0]
        af.u.z = hp_hi | (hp_lo << 16);
    }
    const short8 afrag = af.s;
    const floatx16 zero16 = {0,0,0,0,0,0,0,0,0,0,0,0,0,0,0,0};

    float minsA[16], minsB[16];
    #pragma unroll
    for (int t = 0; t < 16; t++) { minsA[t] = FLT_BIG; minsB[t] = FLT_BIG; }

    __syncthreads();                     // staging complete

    // ---- main loop: this wave's M-quarter, 32 frags of 32 points ----
    const int fbo = mq << 10;            // point offset of quarter
    for (int f = 0; f < 32; f += 8) {
        uint2 bu[8];
        #pragma unroll
        for (int mm = 0; mm < 8; mm++)
            bu[mm] = sld[fbo + ((f + mm) << 5) + row];
        #pragma unroll
        for (int mm = 0; mm < 8; mm++) {
            U4S8 bf;
            bf.u = make_uint4(bu[mm].x, bu[mm].y, 0x3F803F80u, 0u);
            floatx16 d = __builtin_amdgcn_mfma_f32_32x32x16_bf16(
                             afrag, bf.s, zero16, 0, 0, 0);
            if (mm & 1) {
                #pragma unroll
                for (int t = 0; t < 16; t++) minsB[t] = fminf(minsB[t], d[t]);
            } else {
                #pragma unroll
                for (int t = 0; t < 16; t++) minsA[t] = fminf(minsA[t], d[t]);
            }
        }
    }

    // ---- reduce over the 32 cols (within each 32-lane half) ----
    #pragma unroll
    for (int t = 0; t < 16; t++) {
        float v = fminf(minsA[t], minsB[t]);
        v = fminf(v, __shfl_xor(v, 1));
        v = fminf(v, __shfl_xor(v, 2));
        v = fminf(v, __shfl_xor(v, 4));
        v = fminf(v, __shfl_xor(v, 8));
        v = fminf(v, __shfl_xor(v, 16));
        minsA[t] = v;
    }
    // rows for reg t: (t&3) + 8*(t>>2) + 4*half
    if (row == 0) {
        #pragma unroll
        for (int t = 0; t < 16; t++)
            smin[wv][(t & 3) + 8 * (t >> 2) + 4 * half] = minsA[t];
    }
    __syncthreads();

    // combine the 4 M-quarters for each of the 4 ray groups
    if (tid < 128) {
        const int rg2 = tid >> 5;
        const int rr  = tid & 31;
        const float v = fminf(fminf(smin[rg2][rr],      smin[rg2 + 4][rr]),
                              fminf(smin[rg2 + 8][rr],  smin[rg2 + 12][rr]));
        d0[(size_t)b * N + nbase + tid] = fmaxf(2.0f * v, 0.0f);
    }
}

// Kernel B: per-batch histogram select (byte-identical to the verified version).
__global__ __launch_bounds__(256, 1) void select_mean_kernel(
    const float* __restrict__ d0,
    float* __restrict__ out,
    int N, int K)
{
    const int b   = blockIdx.x;
    const int tid = threadIdx.x;

    extern __shared__ unsigned int hist[];   // HIST_BINS
    __shared__ unsigned int spart[256];
    __shared__ unsigned int s_selbin, s_krem;
    __shared__ unsigned int subcnt[32];
    __shared__ float        subsum[32];
    __shared__ float        s_below;

    for (int t2 = tid; t2 < HIST_BINS; t2 += 256) hist[t2] = 0u;
    if (tid < 32) { subcnt[tid] = 0u; subsum[tid] = 0.0f; }
    if (tid == 0) s_below = 0.0f;
    __syncthreads();

    unsigned int key[16];
    #pragma unroll
    for (int t2 = 0; t2 < 16; t2++)
        key[t2] = __float_as_uint(d0[(size_t)b * N + t2 * 256 + tid]);
    #pragma unroll
    for (int t2 = 0; t2 < 16; t2++)
        atomicAdd(&hist[key[t2] >> 18], 1u);
    __syncthreads();

    unsigned int psum = 0u;
    #pragma unroll 8
    for (int i2 = 0; i2 < 64; i2++)
        psum += hist[(tid << 6) + ((i2 + tid) & 63)];
    spart[tid] = psum;
    __syncthreads();

    unsigned int cbef = 0u;
    for (int i2 = 0; i2 < tid; i2++) cbef += spart[i2];
    if (cbef < (unsigned int)K && (unsigned int)K <= cbef + psum) {
        unsigned int k2 = (unsigned int)K - cbef;
        unsigned int sel = 0u;
        for (int i2 = 0; i2 < 64; i2++) {
            unsigned int h = hist[(tid << 6) + i2];
            if (k2 <= h) { sel = (tid << 6) + i2; break; }
            k2 -= h;
        }
        s_selbin = sel;
        s_krem   = k2;
    }
    __syncthreads();

    const unsigned int selbin = s_selbin;
    float sumb = 0.0f;
    #pragma unroll
    for (int t2 = 0; t2 < 16; t2++) {
        const unsigned int bin = key[t2] >> 18;
        const float v = __uint_as_float(key[t2]);
        if (bin < selbin) sumb += v;
        if (bin == selbin) {
            const unsigned int sub = (key[t2] >> 13) & 31u;
            atomicAdd(&subcnt[sub], 1u);
            atomicAdd(&subsum[sub], v);
        }
    }
    atomicAdd(&s_below, sumb);
    __syncthreads();

    if (tid == 0) {
        unsigned int k2 = s_krem;
        float s = s_below;
        for (int i2 = 0; i2 < 32; i2++) {
            unsigned int h = subcnt[i2];
            if (k2 <= h) {
                s += (h ? (subsum[i2] * ((float)k2 / (float)h)) : 0.0f);
                break;
            }
            s += subsum[i2];
            k2 -= h;
        }
        out[b] = 2.0f * s / (float)K;
    }
}

extern "C" void kernel_launch(void* const* d_in, const int* in_sizes, int n_in,
                              void* d_out, int out_size, void* d_ws, size_t ws_size,
                              hipStream_t stream)
{
    const float* c   = (const float*)d_in[0];
    const float* dep = (const float*)d_in[1];
    const float* pc  = (const float*)d_in[2];
    float* out = (float*)d_out;

    const int B = in_sizes[0] / 25;
    const int N = in_sizes[1] / B;     // 4096 (= 16*256, assumed by kernel B)
    const int M = in_sizes[2] / (3 * B);
    int R = 1; while (R * R < N) R++;
    const int K = ((N < M) ? N : M) / 2;

    float* d0 = (float*)d_ws;          // B*N floats of scratch

    dim3 gridA(N / 128, B);
    size_t ldsA = (size_t)M * sizeof(uint2);   // 32KB
    hipLaunchKernelGGL(chamfer_mfma_kernel, gridA, dim3(1024), ldsA, stream,
                       c, dep, pc, d0, N, M, R);

    size_t ldsB = (size_t)HIST_BINS * sizeof(unsigned int);
    hipLaunchKernelGGL(select_mean_kernel, dim3(B), dim3(256), ldsB, stream,
                       d0, out, N, K);
}

// Round 5
// 78.792 us; speedup vs baseline: 1.4142x; 1.0365x over previous
//
#include <hip/hip_runtime.h>
#include <math.h>

#define FLT_BIG 3.0e38f
#define HIST_BINS 16384   // float bits >> 18 : sign(0)+exp(8)+mant(5)

typedef short short8 __attribute__((ext_vector_type(8)));
typedef float floatx16 __attribute__((ext_vector_type(16)));

union U4S8 { uint4 u; short8 s; };

// round-to-nearest-even f32 -> bf16 bits
static __device__ __forceinline__ unsigned int f2bf(float f) {
    unsigned int u = __float_as_uint(f);
    return (u + 0x7FFFu + ((u >> 16) & 1u)) >> 16;
}
static __device__ __forceinline__ float bf2f(unsigned int b) {
    return __uint_as_float(b << 16);
}

// Kernel A (v5): chamfer via MFMA 32x32x16, ZERO staging.
//   D[i][j] = -p_i.q_j + 0.5|q_j|^2 + 0.5|p_i|^2 = 0.5 d^2
// K-slots (k=0..7): A=[-p.x,-p.y,-p.z, 1, hp_hi, hp_lo, 0, 0]
//                   B=[ q.x, q.y, q.z, hq,  1,    1,   0, 0]
// B-fragments are built IN-REGISTER from direct global loads of pc (L2-hot,
// 48KB/batch): no LDS staging, no staging barrier, no pack kernel.
// r0/r3/r4 showed staged variants all tie; this removes both the barrier
// (r0/r4's serialization) and the extra dispatch (r3's gap).
// Block 256 = 4 waves, all on the same 32 rays; wave wv takes M-quarter wv.
// Grid (N/32, B) = 1024 blocks -> 4 blocks/CU, 16 waves/CU.
__global__ __launch_bounds__(256, 4) void chamfer_mfma_kernel(
    const float* __restrict__ cparam,   // B x 25
    const float* __restrict__ depth,    // B x N
    const float* __restrict__ pc,       // B x M x 3
    float* __restrict__ d0,             // B x N (clamped >= 0)
    int N, int M, int R)
{
    const int b    = blockIdx.y;
    const int tid  = threadIdx.x;
    const int lane = tid & 63;
    const int wv   = tid >> 6;           // wave 0..3 -> M-quarter
    const int row  = lane & 31;          // A-row / B-col / D-col
    const int half = lane >> 5;          // k-group: 0 -> k0..7, 1 -> k8..15

    __shared__ float smin[4][32];

    // ---- camera + per-lane ray (same 32 rays for all 4 waves) ----
    const float* cb = cparam + (size_t)b * 25;
    const float fx = cb[16], sk = cb[17], cx = cb[18];
    const float fy = cb[20], cy = cb[21];

    const int nbase = blockIdx.x * 32;
    const int n  = nbase + row;
    const int i0 = n / R;
    const int j0 = n - i0 * R;
    const float x_cam = (j0 + 0.5f) / (float)R;
    const float y_cam = (i0 + 0.5f) / (float)R;
    const float x_lift = (x_cam - cx + cy * sk / fy - sk * y_cam / fy) / fx;
    const float y_lift = (y_cam - cy) / fy;
    const float dxw = cb[0] * x_lift + cb[1] * y_lift + cb[2];
    const float dyw = cb[4] * x_lift + cb[5] * y_lift + cb[6];
    const float dzw = cb[8] * x_lift + cb[9] * y_lift + cb[10];
    const float inv = 1.0f / sqrtf(dxw * dxw + dyw * dyw + dzw * dzw);
    const float dep = depth[(size_t)b * N + n];
    const float px = cb[3]  + dep * dxw * inv;
    const float py = cb[7]  + dep * dyw * inv;
    const float pz = cb[11] + dep * dzw * inv;

    const float hp = 0.5f * (px * px + py * py + pz * pz);
    const unsigned int hp_hi = f2bf(hp);
    const unsigned int hp_lo = f2bf(hp - bf2f(hp_hi));

    U4S8 af;
    af.u = make_uint4(0u, 0u, 0u, 0u);
    if (half == 0) {                     // k=8..15 (upper lanes) stay zero
        af.u.x = f2bf(-px) | (f2bf(-py) << 16);
        af.u.y = f2bf(-pz) | (0x3F80u << 16);      // [-pz, 1.0]
        af.u.z = hp_hi | (hp_lo << 16);
    }
    const short8 afrag = af.s;
    const floatx16 zero16 = {0,0,0,0,0,0,0,0,0,0,0,0,0,0,0,0};

    float minsA[16], minsB[16];
    #pragma unroll
    for (int t = 0; t < 16; t++) { minsA[t] = FLT_BIG; minsB[t] = FLT_BIG; }

    // ---- main loop: this wave's M-quarter, 32 frags of 32 points ----
    // lane 'row' always reads point (f<<5)+row -> 32 lanes read 384B
    // contiguous per frag (3 dwords/lane, stride 12B): coalesced, L2-hot.
    const float* qb = pc + ((size_t)b * M + ((size_t)wv << 10)) * 3;
    for (int f = 0; f < 32; f += 8) {
        float qx[8], qy[8], qz[8];
        #pragma unroll
        for (int mm = 0; mm < 8; mm++) {
            const int p = (((f + mm) << 5) + row) * 3;
            qx[mm] = qb[p + 0];
            qy[mm] = qb[p + 1];
            qz[mm] = qb[p + 2];
        }
        #pragma unroll
        for (int mm = 0; mm < 8; mm++) {
            const float x = qx[mm], y = qy[mm], z = qz[mm];
            const float hq = 0.5f * (x * x + y * y + z * z);
            U4S8 bf;
            bf.u.x = f2bf(x) | (f2bf(y) << 16);
            bf.u.y = f2bf(z) | (f2bf(hq) << 16);
            bf.u.z = 0x3F803F80u;        // [1.0, 1.0] multiplies hp_hi, hp_lo
            bf.u.w = 0u;
            floatx16 d = __builtin_amdgcn_mfma_f32_32x32x16_bf16(
                             afrag, bf.s, zero16, 0, 0, 0);
            if (mm & 1) {
                #pragma unroll
                for (int t = 0; t < 16; t++) minsB[t] = fminf(minsB[t], d[t]);
            } else {
                #pragma unroll
                for (int t = 0; t < 16; t++) minsA[t] = fminf(minsA[t], d[t]);
            }
        }
    }

    // ---- reduce over the 32 cols (within each 32-lane half) ----
    #pragma unroll
    for (int t = 0; t < 16; t++) {
        float v = fminf(minsA[t], minsB[t]);
        v = fminf(v, __shfl_xor(v, 1));
        v = fminf(v, __shfl_xor(v, 2));
        v = fminf(v, __shfl_xor(v, 4));
        v = fminf(v, __shfl_xor(v, 8));
        v = fminf(v, __shfl_xor(v, 16));
        minsA[t] = v;
    }
    // rows for reg t: (t&3) + 8*(t>>2) + 4*half
    if (row == 0) {
        #pragma unroll
        for (int t = 0; t < 16; t++)
            smin[wv][(t & 3) + 8 * (t >> 2) + 4 * half] = minsA[t];
    }
    __syncthreads();

    // combine the 4 M-quarters
    if (tid < 32) {
        const float v = fminf(fminf(smin[0][tid], smin[1][tid]),
                              fminf(smin[2][tid], smin[3][tid]));
        d0[(size_t)b * N + nbase + tid] = fmaxf(2.0f * v, 0.0f);
    }
}

// Kernel B (v2): per-batch histogram select, 1024 threads.
// Same algorithm/binning as the verified 256-thread version, but:
//  - hist zero & psum phases are 4x shorter (16 ops/thread, not 64)
//  - O(tid) serial prefix loop replaced by shuffle scan + 16-wave scan
//  - s_below gets one atomic per wave (wave-reduced), not one per thread
__global__ __launch_bounds__(1024, 1) void select_mean_kernel(
    const float* __restrict__ d0,
    float* __restrict__ out,
    int N, int K)
{
    const int b    = blockIdx.x;
    const int tid  = threadIdx.x;
    const int lane = tid & 63;
    const int w    = tid >> 6;               // 16 waves

    extern __shared__ unsigned int hist[];   // HIST_BINS
    __shared__ unsigned int wsums[16];
    __shared__ unsigned int s_selbin, s_krem;
    __shared__ unsigned int subcnt[32];
    __shared__ float        subsum[32];
    __shared__ float        s_below;

    #pragma unroll
    for (int i = 0; i < 16; i++) hist[(i << 10) + tid] = 0u;
    if (tid < 32) { subcnt[tid] = 0u; subsum[tid] = 0.0f; }
    if (tid == 0) s_below = 0.0f;
    __syncthreads();

    unsigned int key[4];
    #pragma unroll
    for (int t = 0; t < 4; t++)
        key[t] = __float_as_uint(d0[(size_t)b * N + (t << 10) + tid]);
    #pragma unroll
    for (int t = 0; t < 4; t++)
        atomicAdd(&hist[key[t] >> 18], 1u);
    __syncthreads();

    // per-thread total of its 16 bins (rotated to limit bank conflicts)
    unsigned int psum = 0u;
    #pragma unroll
    for (int i = 0; i < 16; i++)
        psum += hist[(tid << 4) + ((i + tid) & 15)];

    // exclusive prefix of psum across 1024 threads: wave scan + wave-sum scan
    unsigned int inc = psum;
    #pragma unroll
    for (int dd = 1; dd < 64; dd <<= 1) {
        unsigned int y = __shfl_up(inc, dd);
        if (lane >= dd) inc += y;
    }
    if (lane == 63) wsums[w] = inc;
    __syncthreads();
    if (tid < 16) {
        const unsigned int v = wsums[tid];
        unsigned int in2 = v;
        #pragma unroll
        for (int dd = 1; dd < 16; dd <<= 1) {
            unsigned int y = __shfl_up(in2, dd);
            if ((int)tid >= dd) in2 += y;
        }
        wsums[tid] = in2 - v;                 // exclusive wave base
    }
    __syncthreads();
    const unsigned int cbef = wsums[w] + (inc - psum);

    if (cbef < (unsigned int)K && (unsigned int)K <= cbef + psum) {
        unsigned int k2 = (unsigned int)K - cbef;
        unsigned int sel = 0u;
        for (int i = 0; i < 16; i++) {
            unsigned int h = hist[(tid << 4) + i];
            if (k2 <= h) { sel = (tid << 4) + i; break; }
            k2 -= h;
        }
        s_selbin = sel;
        s_krem   = k2;
    }
    __syncthreads();

    const unsigned int selbin = s_selbin;
    float sumb = 0.0f;
    #pragma unroll
    for (int t = 0; t < 4; t++) {
        const unsigned int bin = key[t] >> 18;
        const float v = __uint_as_float(key[t]);
        if (bin < selbin) sumb += v;
        if (bin == selbin) {
            const unsigned int sub = (key[t] >> 13) & 31u;
            atomicAdd(&subcnt[sub], 1u);
            atomicAdd(&subsum[sub], v);
        }
    }
    // one atomic per wave for the below-bin sum
    #pragma unroll
    for (int dd = 32; dd; dd >>= 1) sumb += __shfl_xor(sumb, dd);
    if (lane == 0) atomicAdd(&s_below, sumb);
    __syncthreads();

    if (tid == 0) {
        unsigned int k2 = s_krem;
        float s = s_below;
        for (int i2 = 0; i2 < 32; i2++) {
            unsigned int h = subcnt[i2];
            if (k2 <= h) {
                s += (h ? (subsum[i2] * ((float)k2 / (float)h)) : 0.0f);
                break;
            }
            s += subsum[i2];
            k2 -= h;
        }
        out[b] = 2.0f * s / (float)K;
    }
}

extern "C" void kernel_launch(void* const* d_in, const int* in_sizes, int n_in,
                              void* d_out, int out_size, void* d_ws, size_t ws_size,
                              hipStream_t stream)
{
    const float* c   = (const float*)d_in[0];
    const float* dep = (const float*)d_in[1];
    const float* pc  = (const float*)d_in[2];
    float* out = (float*)d_out;

    const int B = in_sizes[0] / 25;
    const int N = in_sizes[1] / B;     // 4096 (= 4*1024, assumed by kernel B)
    const int M = in_sizes[2] / (3 * B);
    int R = 1; while (R * R < N) R++;
    const int K = ((N < M) ? N : M) / 2;

    float* d0 = (float*)d_ws;          // B*N floats of scratch

    dim3 gridA(N / 32, B);
    hipLaunchKernelGGL(chamfer_mfma_kernel, gridA, dim3(256), 0, stream,
                       c, dep, pc, d0, N, M, R);

    size_t ldsB = (size_t)HIST_BINS * sizeof(unsigned int);
    hipLaunchKernelGGL(select_mean_kernel, dim3(B), dim3(1024), ldsB, stream,
                       d0, out, N, K);
}